// Round 1
// baseline (172.609 us; speedup 1.0000x reference)
//
#include <hip/hip_runtime.h>
#include <math.h>

#define NJ 14
#define NE (NJ * 3)   // 42 floats per item per tensor
#define IPB 64        // items per block == blockDim.x
#define LSTR 65       // LDS row stride in floats (64 + 1 pad)

// One cyclic Jacobi rotation on symmetric A, accumulating into V.
// Template indices keep everything in registers (no dynamic indexing).
template <int p, int q, int r>
__device__ __forceinline__ void jrot(float A[3][3], float V[3][3]) {
    float apq = A[p][q];
    if (fabsf(apq) > 1e-20f) {
        float tau = (A[q][q] - A[p][p]) / (2.0f * apq);
        float t = copysignf(1.0f, tau) / (fabsf(tau) + sqrtf(1.0f + tau * tau));
        float c = 1.0f / sqrtf(1.0f + t * t);
        float s = t * c;
        float app = A[p][p], aqq = A[q][q];
        A[p][p] = app - t * apq;
        A[q][q] = aqq + t * apq;
        A[p][q] = 0.0f;
        A[q][p] = 0.0f;
        float arp = A[r][p], arq = A[r][q];
        A[r][p] = c * arp - s * arq;
        A[p][r] = A[r][p];
        A[r][q] = s * arp + c * arq;
        A[q][r] = A[r][q];
#pragma unroll
        for (int k = 0; k < 3; ++k) {
            float vkp = V[k][p], vkq = V[k][q];
            V[k][p] = c * vkp - s * vkq;
            V[k][q] = s * vkp + c * vkq;
        }
    }
}

__global__ __launch_bounds__(IPB) void pampjpe_kernel(
    const float* __restrict__ pred, const float* __restrict__ gt,
    float* __restrict__ out, int n_items) {
    // LDS layout: [elem][item], stride 65 -> conflict-free per-elem reads
    __shared__ float sp[NE * LSTR];
    __shared__ float sg[NE * LSTR];

    const int tid = threadIdx.x;
    const long long base = (long long)blockIdx.x * IPB * NE;
    const int item0 = blockIdx.x * IPB;

    // ---- stage: coalesced global dword loads, transposed LDS store ----
#pragma unroll
    for (int it = 0; it < NE; ++it) {
        int idx = it * IPB + tid;          // 0 .. 2687
        int item = idx / NE;               // const-div -> magic mul
        int e = idx - item * NE;
        if (item0 + item < n_items) {
            sp[e * LSTR + item] = pred[base + idx];
            sg[e * LSTR + item] = gt[base + idx];
        }
    }
    __syncthreads();

    const int me = item0 + tid;
    if (me >= n_items) return;

    // ---- pass A: moments ----
    float Sp0 = 0.f, Sp1 = 0.f, Sp2 = 0.f;
    float Sg0 = 0.f, Sg1 = 0.f, Sg2 = 0.f;
    float pp = 0.f;
    float M[3][3] = {{0.f, 0.f, 0.f}, {0.f, 0.f, 0.f}, {0.f, 0.f, 0.f}};
#pragma unroll
    for (int j = 0; j < NJ; ++j) {
        float px = sp[(3 * j + 0) * LSTR + tid];
        float py = sp[(3 * j + 1) * LSTR + tid];
        float pz = sp[(3 * j + 2) * LSTR + tid];
        float gx = sg[(3 * j + 0) * LSTR + tid];
        float gy = sg[(3 * j + 1) * LSTR + tid];
        float gz = sg[(3 * j + 2) * LSTR + tid];
        Sp0 += px; Sp1 += py; Sp2 += pz;
        Sg0 += gx; Sg1 += gy; Sg2 += gz;
        pp += px * px + py * py + pz * pz;
        M[0][0] += px * gx; M[0][1] += px * gy; M[0][2] += px * gz;
        M[1][0] += py * gx; M[1][1] += py * gy; M[1][2] += py * gz;
        M[2][0] += pz * gx; M[2][1] += pz * gy; M[2][2] += pz * gz;
    }
    const float invJ = 1.0f / (float)NJ;
    float mp[3] = {Sp0 * invJ, Sp1 * invJ, Sp2 * invJ};
    float mg[3] = {Sg0 * invJ, Sg1 * invJ, Sg2 * invJ};

    float K[3][3];
#pragma unroll
    for (int i = 0; i < 3; ++i)
#pragma unroll
        for (int j = 0; j < 3; ++j)
            K[i][j] = M[i][j] - (float)NJ * mp[i] * mg[j];
    float var1 = pp - (float)NJ * (mp[0] * mp[0] + mp[1] * mp[1] + mp[2] * mp[2]);
    var1 = fmaxf(var1, 1e-30f);

    // ---- A = K^T K (symmetric), Jacobi eigendecomposition ----
    float A[3][3];
#pragma unroll
    for (int i = 0; i < 3; ++i)
#pragma unroll
        for (int j = 0; j < 3; ++j)
            A[i][j] = K[0][i] * K[0][j] + K[1][i] * K[1][j] + K[2][i] * K[2][j];
    float V[3][3] = {{1.f, 0.f, 0.f}, {0.f, 1.f, 0.f}, {0.f, 0.f, 1.f}};
#pragma unroll
    for (int sweep = 0; sweep < 8; ++sweep) {
        jrot<0, 1, 2>(A, V);
        jrot<0, 2, 1>(A, V);
        jrot<1, 2, 0>(A, V);
    }
    float lam0 = A[0][0], lam1 = A[1][1], lam2 = A[2][2];

    // sort eigenpairs descending (columns of V)
#define SWAPCOL(la, lb, a, b)                                     \
    {                                                             \
        float _t;                                                 \
        _t = la; la = lb; lb = _t;                                \
        _t = V[0][a]; V[0][a] = V[0][b]; V[0][b] = _t;            \
        _t = V[1][a]; V[1][a] = V[1][b]; V[1][b] = _t;            \
        _t = V[2][a]; V[2][a] = V[2][b]; V[2][b] = _t;            \
    }
    if (lam0 < lam1) SWAPCOL(lam0, lam1, 0, 1)
    if (lam0 < lam2) SWAPCOL(lam0, lam2, 0, 2)
    if (lam1 < lam2) SWAPCOL(lam1, lam2, 1, 2)
#undef SWAPCOL

    float v0[3] = {V[0][0], V[1][0], V[2][0]};
    float v1[3] = {V[0][1], V[1][1], V[2][1]};
    float v2[3] = {V[0][2], V[1][2], V[2][2]};

    // force det(V) = +1 (flip eigenvector of smallest eigenvalue)
    float cxx = v0[1] * v1[2] - v0[2] * v1[1];
    float cxy = v0[2] * v1[0] - v0[0] * v1[2];
    float cxz = v0[0] * v1[1] - v0[1] * v1[0];
    float detv = cxx * v2[0] + cxy * v2[1] + cxz * v2[2];
    if (detv < 0.f) { v2[0] = -v2[0]; v2[1] = -v2[1]; v2[2] = -v2[2]; }

    // U: u1 = normalize(K v0); u2 = GS(K v1); u3 = u1 x u2  -> det(U)=+1
    float w0[3], w1[3];
#pragma unroll
    for (int i = 0; i < 3; ++i) {
        w0[i] = K[i][0] * v0[0] + K[i][1] * v0[1] + K[i][2] * v0[2];
        w1[i] = K[i][0] * v1[0] + K[i][1] * v1[1] + K[i][2] * v1[2];
    }
    float inv0 = 1.0f / sqrtf(fmaxf(w0[0] * w0[0] + w0[1] * w0[1] + w0[2] * w0[2], 1e-30f));
    float u1[3] = {w0[0] * inv0, w0[1] * inv0, w0[2] * inv0};
    float d1 = u1[0] * w1[0] + u1[1] * w1[1] + u1[2] * w1[2];
    w1[0] -= d1 * u1[0]; w1[1] -= d1 * u1[1]; w1[2] -= d1 * u1[2];
    float inv1 = 1.0f / sqrtf(fmaxf(w1[0] * w1[0] + w1[1] * w1[1] + w1[2] * w1[2], 1e-30f));
    float u2[3] = {w1[0] * inv1, w1[1] * inv1, w1[2] * inv1};
    float u3[3] = {u1[1] * u2[2] - u1[2] * u2[1],
                   u1[2] * u2[0] - u1[0] * u2[2],
                   u1[0] * u2[1] - u1[1] * u2[0]};

    // R = V U^T  (handles the reflection case automatically)
    float R[3][3];
#pragma unroll
    for (int i = 0; i < 3; ++i) {
        R[i][0] = v0[i] * u1[0] + v1[i] * u2[0] + v2[i] * u3[0];
        R[i][1] = v0[i] * u1[1] + v1[i] * u2[1] + v2[i] * u3[1];
        R[i][2] = v0[i] * u1[2] + v1[i] * u2[2] + v2[i] * u3[2];
    }
    float trRK = 0.f;
#pragma unroll
    for (int i = 0; i < 3; ++i)
#pragma unroll
        for (int j = 0; j < 3; ++j)
            trRK += R[i][j] * K[j][i];
    float scale = trRK / var1;

    // ---- pass B: loss = mean_j || scale * R * x1_j - x2_j || ----
    float acc = 0.f;
#pragma unroll
    for (int j = 0; j < NJ; ++j) {
        float x0 = sp[(3 * j + 0) * LSTR + tid] - mp[0];
        float x1 = sp[(3 * j + 1) * LSTR + tid] - mp[1];
        float x2 = sp[(3 * j + 2) * LSTR + tid] - mp[2];
        float y0 = sg[(3 * j + 0) * LSTR + tid] - mg[0];
        float y1 = sg[(3 * j + 1) * LSTR + tid] - mg[1];
        float y2 = sg[(3 * j + 2) * LSTR + tid] - mg[2];
        float e0 = scale * (R[0][0] * x0 + R[0][1] * x1 + R[0][2] * x2) - y0;
        float e1 = scale * (R[1][0] * x0 + R[1][1] * x1 + R[1][2] * x2) - y1;
        float e2 = scale * (R[2][0] * x0 + R[2][1] * x1 + R[2][2] * x2) - y2;
        acc += sqrtf(e0 * e0 + e1 * e1 + e2 * e2);
    }
    out[me] = acc * invJ;
}

extern "C" void kernel_launch(void* const* d_in, const int* in_sizes, int n_in,
                              void* d_out, int out_size, void* d_ws, size_t ws_size,
                              hipStream_t stream) {
    const float* pred = (const float*)d_in[0];
    const float* gt = (const float*)d_in[1];
    float* out = (float*)d_out;
    int n_items = in_sizes[0] / NE;  // 262144
    int grid = (n_items + IPB - 1) / IPB;
    pampjpe_kernel<<<grid, IPB, 0, stream>>>(pred, gt, out, n_items);
}